// Round 5
// baseline (451.904 us; speedup 1.0000x reference)
//
#include <hip/hip_runtime.h>
#include <hip/hip_cooperative_groups.h>
namespace cg = cooperative_groups;

// ---------------------------------------------------------------- constants
#define T_N   262144
#define D_IN  128
#define A_DIM 8
#define GAMMA 0.99f
#define EPS_C 0.2f
#define C_GL  0.9405f                 // GAMMA*LMBD
#define HALF_LOG_2PI 0.9189385332f
#define SCALE2 2.8853900817779268f    // 2*log2(e): pre-activation scale for exp2-tanh
#define N_SB  728                     // state-role blocks (tiles stride)
#define N_NB  296                     // next-role blocks
#define NPREP 144u                    // prep blocks (144*512 = 73728 weight elems)

typedef __attribute__((ext_vector_type(8))) short short8;
typedef __attribute__((ext_vector_type(4))) float f32x4;

__device__ __forceinline__ unsigned short f2bf(float f) {   // RNE (prep only)
  unsigned int u = __float_as_uint(f);
  u += 0x7FFFu + ((u >> 16) & 1u);
  return (unsigned short)(u >> 16);
}
// pack two f32 -> two bf16 (truncate) in ONE v_perm_b32
__device__ __forceinline__ unsigned int pack_bf2(float lo, float hi) {
  return __builtin_amdgcn_perm(__float_as_uint(hi), __float_as_uint(lo), 0x07060302u);
}
__device__ __forceinline__ unsigned short bf_trunc(float f) {
  return (unsigned short)(__float_as_uint(f) >> 16);
}
// a = 2*log2(e)*x (weights pre-scaled); returns tanh(x).
__device__ __forceinline__ float tanh_pre(float a) {
  float e = __builtin_amdgcn_exp2f(a);
  return 1.f - 2.f * __builtin_amdgcn_rcpf(e + 1.f);
}
template <int CTRL>
__device__ __forceinline__ float dpp_add(float p) {
  return p + __int_as_float(__builtin_amdgcn_update_dpp(
                 0, __float_as_int(p), CTRL, 0xF, 0xF, true));
}
// sum over each 16-lane row; total lands at lane%16 == 15
__device__ __forceinline__ float row16_sum(float p) {
  p = dpp_add<0x111>(p); p = dpp_add<0x112>(p);
  p = dpp_add<0x114>(p); p = dpp_add<0x118>(p);
  return p;
}
// sum over each 8-lane group; total at all 8 lanes (xor1, xor2, half-mirror)
__device__ __forceinline__ float xor8_sum(float p) {
  p = dpp_add<0xB1>(p); p = dpp_add<0x4E>(p); p = dpp_add<0x141>(p);
  return p;
}

// ---------------------------------------------------------------- fused GEMM kernel
// grid 1024 x 512. Blocks 0..143 first convert weights (Wc1Ts/W1Ts: [H][D] bf16
// pre-scaled by 2log2e; H1: [16][256] actor head), release a device-scope flag;
// everyone acquire-spins before loading B-fragments (producers are the first-
// launched blocks -> progress guaranteed). Then:
//   bid <  N_SB: state path — waves 0-3 critic(state)->v0, waves 4-7 actor->ratio
//   bid >= N_SB: next path  — 8 waves critic(next_state)->v1 (32-col slices)
__global__ __launch_bounds__(512, 4) void k_fused(
    const float* __restrict__ state, const float* __restrict__ next_state,
    const float* __restrict__ action, const float* __restrict__ beta_lp,
    const float* __restrict__ Wc1, const float* __restrict__ W1,
    const float* __restrict__ Wmu, const float* __restrict__ Wlv,
    const float* __restrict__ bc1, const float* __restrict__ b1,
    const float* __restrict__ Wc2, const float* __restrict__ bc2,
    const float* __restrict__ bmu, const float* __restrict__ blv,
    unsigned short* __restrict__ Wc1Ts, unsigned short* __restrict__ W1Ts,
    unsigned short* __restrict__ H1,
    float* __restrict__ v0out, float* __restrict__ v1out,
    float* __restrict__ ratio, float* __restrict__ accs) {
  const int bid = blockIdx.x;
  const int tid = threadIdx.x;
  const int lane = tid & 63;
  const int wv   = tid >> 6;          // 0..7
  const int c    = lane & 15;
  const int quad = lane >> 4;
  unsigned int* flagp = (unsigned int*)accs + 8;

  __shared__ unsigned short sh_x[32 * 136];   // 8.5 KB
  __shared__ unsigned short sh_h[32 * 264];   // 16.5 KB (actor hidden)
  __shared__ float sh_hb[4 * 32 * 16];        // 8 KB (actor head partials)
  __shared__ float sh_v[32 * 8];              // 1 KB (critic partials)

  // ---- inline prep (blocks 0..143)
  if (bid < (int)NPREP) {
    int i = bid * 512 + tid;
    if (i < 32768) {
      int n = i >> 7, k = i & 127;
      Wc1Ts[i] = f2bf(Wc1[k * 256 + n] * SCALE2);
    } else if (i < 65536) {
      int j = i - 32768; int n = j >> 7, k = j & 127;
      W1Ts[j] = f2bf(W1[k * 256 + n] * SCALE2);
    } else if (i < 69632) {
      int j = i - 65536; int h = j >> 8, n = j & 255;
      H1[j] = (h < 8) ? f2bf(Wmu[n * 8 + h]) : f2bf(Wlv[n * 8 + (h - 8)]);
    }
    __syncthreads();
    if (tid == 0)
      __hip_atomic_fetch_add(flagp, 1u, __ATOMIC_RELEASE, __HIP_MEMORY_SCOPE_AGENT);
  }

  const bool is_state = bid < N_SB;
  const float* Xbase = is_state ? state : next_state;
  const int stride = is_state ? N_SB : N_NB;
  int t = is_state ? bid : (bid - N_SB);

  // ---- prefetch first X tile (independent of prep)
  float4 rbuf[2];
  {
    const float4* Xv = (const float4*)(Xbase + (size_t)t * 32 * D_IN);
    rbuf[0] = Xv[tid]; rbuf[1] = Xv[tid + 512];
  }

  // ---- acquire weights
  if (tid == 0) {
    while (__hip_atomic_load(flagp, __ATOMIC_ACQUIRE, __HIP_MEMORY_SCOPE_AGENT) < NPREP)
      __builtin_amdgcn_s_sleep(1);
  }
  __syncthreads();

  if (is_state) {
    const int wl = wv & 3;
    const unsigned short* WT = (wv < 4) ? Wc1Ts : W1Ts;
    const float* bias = (wv < 4) ? bc1 : b1;
    short8 bfrag[4][4];
    float bias_c[4], wc2_c[4];
#pragma unroll
    for (int ct = 0; ct < 4; ++ct) {
      int n = wl * 64 + ct * 16 + c;
      bias_c[ct] = bias[n] * SCALE2;
      wc2_c[ct]  = Wc2[n];
#pragma unroll
      for (int ki = 0; ki < 4; ++ki)
        bfrag[ct][ki] = *(const short8*)(WT + n * 128 + ki * 32 + quad * 8);
    }
    const float vbias = bc2[0];
    const int aa = tid & 7;
    const float bmu_a = bmu[aa], blv_a = blv[aa];

    for (; t < 8192; t += N_SB) {
      const int r0 = t * 32;
      // stage regs -> LDS bf16 (perm-truncate)
#pragma unroll
      for (int j = 0; j < 2; ++j) {
        int e4 = tid + j * 512;
        int row = e4 >> 5, c4 = e4 & 31;
        uint2 u;
        u.x = pack_bf2(rbuf[j].x, rbuf[j].y);
        u.y = pack_bf2(rbuf[j].z, rbuf[j].w);
        *(uint2*)(&sh_x[row * 136 + c4 * 4]) = u;
      }
      __syncthreads();                          // barrier1
      int tn = t + N_SB;
      if (tn < 8192) {
        const float4* Xv2 = (const float4*)(state + (size_t)tn * 32 * D_IN);
        rbuf[0] = Xv2[tid]; rbuf[1] = Xv2[tid + 512];
      }
      float fa = 0.f, fb = 0.f;
      if (tid < 256) { fa = action[r0 * 8 + tid]; fb = beta_lp[r0 * 8 + tid]; }

      if (wv < 4) {
        // critic GEMM + fused head
#pragma unroll
        for (int rt = 0; rt < 2; ++rt) {
          f32x4 acc[4];
#pragma unroll
          for (int ct = 0; ct < 4; ++ct) acc[ct] = (f32x4){0.f, 0.f, 0.f, 0.f};
#pragma unroll
          for (int ki = 0; ki < 4; ++ki) {
            short8 a = *(const short8*)(&sh_x[(rt * 16 + c) * 136 + ki * 32 + quad * 8]);
#pragma unroll
            for (int ct = 0; ct < 4; ++ct)
              acc[ct] = __builtin_amdgcn_mfma_f32_16x16x32_bf16(a, bfrag[ct][ki], acc[ct], 0, 0, 0);
          }
#pragma unroll
          for (int r = 0; r < 4; ++r) {
            float p = 0.f;
#pragma unroll
            for (int ct = 0; ct < 4; ++ct)
              p += tanh_pre(acc[ct][r] + bias_c[ct]) * wc2_c[ct];
            p = row16_sum(p);
            if (c == 15) sh_v[(rt * 16 + quad * 4 + r) * 4 + wl] = p;
          }
        }
      } else {
        // actor GEMM -> sh_h
#pragma unroll
        for (int rt = 0; rt < 2; ++rt) {
          f32x4 acc[4];
#pragma unroll
          for (int ct = 0; ct < 4; ++ct) acc[ct] = (f32x4){0.f, 0.f, 0.f, 0.f};
#pragma unroll
          for (int ki = 0; ki < 4; ++ki) {
            short8 a = *(const short8*)(&sh_x[(rt * 16 + c) * 136 + ki * 32 + quad * 8]);
#pragma unroll
            for (int ct = 0; ct < 4; ++ct)
              acc[ct] = __builtin_amdgcn_mfma_f32_16x16x32_bf16(a, bfrag[ct][ki], acc[ct], 0, 0, 0);
          }
#pragma unroll
          for (int ct = 0; ct < 4; ++ct) {
            int col = wl * 64 + ct * 16 + c;
#pragma unroll
            for (int r = 0; r < 4; ++r) {
              int row = rt * 16 + quad * 4 + r;
              sh_h[row * 264 + col] = bf_trunc(tanh_pre(acc[ct][r] + bias_c[ct]));
            }
          }
        }
      }
      __syncthreads();                          // barrier2

      if (wv >= 4) {
        // head GEMM: slice wl owns K-cols [wl*64, +64)
#pragma unroll
        for (int st = 0; st < 2; ++st) {
          f32x4 acc2 = (f32x4){0.f, 0.f, 0.f, 0.f};
#pragma unroll
          for (int k2 = 0; k2 < 2; ++k2) {
            int kofs = wl * 64 + k2 * 32 + quad * 8;
            short8 a2 = *(const short8*)(H1 + c * 256 + kofs);
            short8 b2 = *(const short8*)(&sh_h[(st * 16 + c) * 264 + kofs]);
            acc2 = __builtin_amdgcn_mfma_f32_16x16x32_bf16(a2, b2, acc2, 0, 0, 0);
          }
          *((f32x4*)&sh_hb[((wl * 32) + st * 16 + c) * 16 + quad * 4]) = acc2;
        }
      } else if (tid < 32) {
        v0out[r0 + tid] = sh_v[tid * 4] + sh_v[tid * 4 + 1] + sh_v[tid * 4 + 2] +
                          sh_v[tid * 4 + 3] + vbias;
      }
      __syncthreads();                          // barrier3

      if (tid < 256) {
        int s = tid >> 3;
        float mu = sh_hb[(s)*16 + aa]          + sh_hb[(32 + s) * 16 + aa] +
                   sh_hb[(64 + s) * 16 + aa]   + sh_hb[(96 + s) * 16 + aa] + bmu_a;
        float lv = sh_hb[(s)*16 + 8 + aa]      + sh_hb[(32 + s) * 16 + 8 + aa] +
                   sh_hb[(64 + s) * 16 + 8 + aa] + sh_hb[(96 + s) * 16 + 8 + aa] + blv_a;
        float d = fa - mu;
        float term = -0.5f * d * d * __expf(-lv) - 0.5f * lv - HALF_LOG_2PI - fb;
        term = xor8_sum(term);
        if (aa == 0) ratio[r0 + s] = __expf(term);
      }
    }
  } else {
    // -------- next path: 8 waves critic; wave wv owns cols [wv*32, +32)
    short8 bfrag[2][4];
    float bias_c[2], wc2_c[2];
#pragma unroll
    for (int ct = 0; ct < 2; ++ct) {
      int n = wv * 32 + ct * 16 + c;
      bias_c[ct] = bc1[n] * SCALE2;
      wc2_c[ct]  = Wc2[n];
#pragma unroll
      for (int ki = 0; ki < 4; ++ki)
        bfrag[ct][ki] = *(const short8*)(Wc1Ts + n * 128 + ki * 32 + quad * 8);
    }
    const float vbias = bc2[0];

    for (; t < 8192; t += N_NB) {
      const int r0 = t * 32;
#pragma unroll
      for (int j = 0; j < 2; ++j) {
        int e4 = tid + j * 512;
        int row = e4 >> 5, c4 = e4 & 31;
        uint2 u;
        u.x = pack_bf2(rbuf[j].x, rbuf[j].y);
        u.y = pack_bf2(rbuf[j].z, rbuf[j].w);
        *(uint2*)(&sh_x[row * 136 + c4 * 4]) = u;
      }
      __syncthreads();
      int tn = t + N_NB;
      if (tn < 8192) {
        const float4* Xv2 = (const float4*)(next_state + (size_t)tn * 32 * D_IN);
        rbuf[0] = Xv2[tid]; rbuf[1] = Xv2[tid + 512];
      }

#pragma unroll
      for (int rt = 0; rt < 2; ++rt) {
        f32x4 acc[2];
#pragma unroll
        for (int ct = 0; ct < 2; ++ct) acc[ct] = (f32x4){0.f, 0.f, 0.f, 0.f};
#pragma unroll
        for (int ki = 0; ki < 4; ++ki) {
          short8 a = *(const short8*)(&sh_x[(rt * 16 + c) * 136 + ki * 32 + quad * 8]);
#pragma unroll
          for (int ct = 0; ct < 2; ++ct)
            acc[ct] = __builtin_amdgcn_mfma_f32_16x16x32_bf16(a, bfrag[ct][ki], acc[ct], 0, 0, 0);
        }
#pragma unroll
        for (int r = 0; r < 4; ++r) {
          float p = tanh_pre(acc[0][r] + bias_c[0]) * wc2_c[0] +
                    tanh_pre(acc[1][r] + bias_c[1]) * wc2_c[1];
          p = row16_sum(p);
          if (c == 15) sh_v[(rt * 16 + quad * 4 + r) * 8 + wv] = p;
        }
      }
      __syncthreads();
      if (tid < 32) {
        float s = vbias;
#pragma unroll
        for (int w8 = 0; w8 < 8; ++w8) s += sh_v[tid * 8 + w8];
        v1out[r0 + tid] = s;
      }
    }
  }
}

// ---------------------------------------------------------------- GAE + losses (cooperative):
// 256 blocks x 1024 own elems (+1024 lookahead, c^1024 ~ 5e-28 -> exact trunc).
// adv stays in registers across grid.sync(); no adv array in HBM.
__global__ __launch_bounds__(256) void k_tail(
    const float* __restrict__ reward, const float* __restrict__ v0,
    const float* __restrict__ v1, const float* __restrict__ ratio,
    float* __restrict__ accs, float* __restrict__ out) {
  cg::grid_group grid = cg::this_grid();
  const int j = blockIdx.x, k = threadIdx.x;
  const int base = j * 1024 + k * 8;
  float d[8];
  float s = 0.f, w = 1.f;
#pragma unroll
  for (int i = 0; i < 8; ++i) {
    int idx = base + i;
    float dd = 0.f;
    if (idx < T_N) dd = reward[idx] + GAMMA * v1[idx] - v0[idx];
    d[i] = dd;
    s += w * dd;
    w *= C_GL;
  }
  const float W8 = w;
  __shared__ float Ss[256], Sw[256];
  Ss[k] = s; Sw[k] = W8;
  __syncthreads();
  for (int st = 1; st < 256; st <<= 1) {
    bool has = (k + st) < 256;
    float ns = 0.f, nw = 0.f;
    if (has) { ns = Ss[k] + Sw[k] * Ss[k + st]; nw = Sw[k] * Sw[k + st]; }
    __syncthreads();
    if (has) { Ss[k] = ns; Sw[k] = nw; }
    __syncthreads();
  }
  float g = (k < 255) ? Ss[k + 1] : 0.f;
  float adv[8];
  float sa = 0.f, sq = 0.f;
  if (k < 128) {
#pragma unroll
    for (int i = 7; i >= 0; --i) {
      g = d[i] + C_GL * g;
      float a = g - v0[base + i];
      adv[i] = a;
      sa += a; sq += a * a;
    }
  }
  __syncthreads();
  Ss[k] = sa; Sw[k] = sq;
  __syncthreads();
  for (int off = 128; off > 0; off >>= 1) {
    if (k < off) { Ss[k] += Ss[k + off]; Sw[k] += Sw[k + off]; }
    __syncthreads();
  }
  if (k == 0) {
    atomicAdd(&accs[0], Ss[0]);                 // Σ adv
    atomicAdd(&accs[1], Sw[0]);                 // Σ adv² (= critic_loss)
  }

  grid.sync();

  float sum  = accs[0];
  float mean = sum * (1.f / (float)T_N);
  float var  = (accs[1] - sum * mean) / (float)(T_N - 1);
  float inv  = 1.f / (sqrtf(var) + 1e-7f);
  float sl = 0.f;
  if (k < 128) {
#pragma unroll
    for (int i = 0; i < 8; ++i) {
      float a = (adv[i] - mean) * inv;
      float r = ratio[base + i];
      float rc = fminf(fmaxf(r, 1.f - EPS_C), 1.f + EPS_C);
      sl += -fminf(r * a, rc * a);
    }
  }
  __syncthreads();
  Ss[k] = sl;
  __syncthreads();
  for (int off = 128; off > 0; off >>= 1) {
    if (k < off) Ss[k] += Ss[k + off];
    __syncthreads();
  }
  if (k == 0) atomicAdd(&accs[2], Ss[0]);       // actor_loss

  grid.sync();
  if (j == 0 && k == 0) out[0] = accs[2] + accs[1];
}

// ---------------------------------------------------------------- launch
extern "C" void kernel_launch(void* const* d_in, const int* in_sizes, int n_in,
                              void* d_out, int out_size, void* d_ws, size_t ws_size,
                              hipStream_t stream) {
  const float* state      = (const float*)d_in[0];
  const float* next_state = (const float*)d_in[1];
  const float* action     = (const float*)d_in[2];
  const float* beta_lp    = (const float*)d_in[3];
  const float* reward     = (const float*)d_in[4];
  const float* W1   = (const float*)d_in[5];
  const float* b1   = (const float*)d_in[6];
  const float* Wmu  = (const float*)d_in[7];
  const float* bmu  = (const float*)d_in[8];
  const float* Wlv  = (const float*)d_in[9];
  const float* blv  = (const float*)d_in[10];
  const float* Wc1  = (const float*)d_in[11];
  const float* bc1  = (const float*)d_in[12];
  const float* Wc2  = (const float*)d_in[13];
  const float* bc2  = (const float*)d_in[14];

  char* ws = (char*)d_ws;
  size_t o = 0;
  unsigned short* Wc1Ts = (unsigned short*)(ws + o); o += 65536;
  unsigned short* W1Ts  = (unsigned short*)(ws + o); o += 65536;
  unsigned short* H1    = (unsigned short*)(ws + o); o += 8192;
  float* v0    = (float*)(ws + o); o += (size_t)T_N * 4;
  float* v1    = (float*)(ws + o); o += (size_t)T_N * 4;
  float* ratio = (float*)(ws + o); o += (size_t)T_N * 4;
  float* accs  = (float*)(ws + o); o += 256;

  hipMemsetAsync(accs, 0, 64, stream);          // accs[0..2] + prep flag

  k_fused<<<N_SB + N_NB, 512, 0, stream>>>(
      state, next_state, action, beta_lp, Wc1, W1, Wmu, Wlv,
      bc1, b1, Wc2, bc2, bmu, blv, Wc1Ts, W1Ts, H1, v0, v1, ratio, accs);

  float* outp = (float*)d_out;
  void* cargs[6] = {(void*)&reward, (void*)&v0, (void*)&v1,
                    (void*)&ratio, (void*)&accs, (void*)&outp};
  hipLaunchCooperativeKernel((const void*)k_tail, dim3(256), dim3(256),
                             cargs, 0, stream);
}

// Round 6
// 375.389 us; speedup vs baseline: 1.2038x; 1.2038x over previous
//
#include <hip/hip_runtime.h>

// ---------------------------------------------------------------- constants
#define T_N   262144
#define D_IN  128
#define A_DIM 8
#define GAMMA 0.99f
#define EPS_C 0.2f
#define C_GL  0.9405f                 // GAMMA*LMBD
#define HALF_LOG_2PI 0.9189385332f
#define SCALE2 2.8853900817779268f    // 2*log2(e): pre-activation scale for exp2-tanh
#define ST_TPB 8                      // k_state tiles/block -> 1024 blocks (4/CU)
#define NX_TPB 4                      // k_next tiles/block  -> 2048 blocks (8/CU)
#define HB_S   20                     // sh_hb padded stride (floats)

typedef __attribute__((ext_vector_type(8))) short short8;
typedef __attribute__((ext_vector_type(4))) float f32x4;

__device__ __forceinline__ unsigned short f2bf(float f) {   // RNE (prep only)
  unsigned int u = __float_as_uint(f);
  u += 0x7FFFu + ((u >> 16) & 1u);
  return (unsigned short)(u >> 16);
}
// pack two f32 -> two bf16 (truncate) in ONE v_perm_b32
__device__ __forceinline__ unsigned int pack_bf2(float lo, float hi) {
  return __builtin_amdgcn_perm(__float_as_uint(hi), __float_as_uint(lo), 0x07060302u);
}
__device__ __forceinline__ unsigned short bf_trunc(float f) {
  return (unsigned short)(__float_as_uint(f) >> 16);
}
// a = 2*log2(e)*x (weights pre-scaled); returns tanh(x).
__device__ __forceinline__ float tanh_pre(float a) {
  float e = __builtin_amdgcn_exp2f(a);
  return 1.f - 2.f * __builtin_amdgcn_rcpf(e + 1.f);
}
template <int CTRL>
__device__ __forceinline__ float dpp_add(float p) {
  return p + __int_as_float(__builtin_amdgcn_update_dpp(
                 0, __float_as_int(p), CTRL, 0xF, 0xF, true));
}
// sum over each 16-lane row; total lands at lane%16 == 15
__device__ __forceinline__ float row16_sum(float p) {
  p = dpp_add<0x111>(p); p = dpp_add<0x112>(p);
  p = dpp_add<0x114>(p); p = dpp_add<0x118>(p);
  return p;
}
// sum over each 8-lane group; total at all 8 lanes (xor1, xor2, half-mirror)
__device__ __forceinline__ float xor8_sum(float p) {
  p = dpp_add<0xB1>(p); p = dpp_add<0x4E>(p); p = dpp_add<0x141>(p);
  return p;
}

// ---------------------------------------------------------------- prep:
// Wc1Ts/W1Ts: [H][D] bf16, transposed AND pre-scaled by 2*log2(e).
// H1: [16][256] bf16 actor head (rows0-7 = Wmu^T, 8-15 = Wlv^T). Also zeros accs.
__global__ __launch_bounds__(256) void k_prep(
    const float* __restrict__ Wc1, const float* __restrict__ W1,
    const float* __restrict__ Wmu, const float* __restrict__ Wlv,
    unsigned short* __restrict__ Wc1Ts, unsigned short* __restrict__ W1Ts,
    unsigned short* __restrict__ H1, float* __restrict__ accs) {
  int i = blockIdx.x * 256 + threadIdx.x;
  if (blockIdx.x == 0 && threadIdx.x < 8) ((unsigned int*)accs)[threadIdx.x] = 0u;
  if (i < 32768) {
    int n = i >> 7, k = i & 127;
    Wc1Ts[i] = f2bf(Wc1[k * 256 + n] * SCALE2);
  } else if (i < 65536) {
    int j = i - 32768; int n = j >> 7, k = j & 127;
    W1Ts[j] = f2bf(W1[k * 256 + n] * SCALE2);
  } else if (i < 69632) {
    int j = i - 65536; int h = j >> 8, n = j & 255;
    H1[j] = (h < 8) ? f2bf(Wmu[n * 8 + h]) : f2bf(Wlv[n * 8 + (h - 8)]);
  }
}

// ---------------------------------------------------------------- k_state:
// 1024 persistent blocks x ST_TPB tiles of 32 rows; 512 threads.
// waves 0-3: critic(state)->v0 (64-col slices, fused VALU head);
// waves 4-7: actor(state) hidden -> head MFMA -> ratio.
__global__ __launch_bounds__(512, 4) void k_state(
    const float* __restrict__ state,
    const float* __restrict__ action, const float* __restrict__ beta_lp,
    const unsigned short* __restrict__ Wc1Ts, const unsigned short* __restrict__ W1Ts,
    const unsigned short* __restrict__ H1,
    const float* __restrict__ bc1, const float* __restrict__ b1,
    const float* __restrict__ Wc2, const float* __restrict__ bc2,
    const float* __restrict__ bmu, const float* __restrict__ blv,
    float* __restrict__ v0out, float* __restrict__ ratio) {
  const int tid  = threadIdx.x;
  const int lane = tid & 63;
  const int wv   = tid >> 6;          // 0..7
  const int role = wv >> 2;           // 0 = critic, 1 = actor
  const int wl   = wv & 3;            // slice within role
  const int c    = lane & 15;
  const int quad = lane >> 4;

  __shared__ unsigned short sh_x[32 * 136];   // 8.5 KB
  __shared__ unsigned short sh_h[32 * 264];   // 16.5 KB
  __shared__ float sh_hb[4 * 32 * HB_S];      // 10 KB, padded stride
  __shared__ float sh_v[32 * 4];

  const unsigned short* WT = role ? W1Ts : Wc1Ts;
  const float* bias = role ? b1 : bc1;

  short8 bfrag[4][4];
  float bias_c[4], wc2_c[4];
#pragma unroll
  for (int ct = 0; ct < 4; ++ct) {
    int n = wl * 64 + ct * 16 + c;
    bias_c[ct] = bias[n] * SCALE2;
    wc2_c[ct]  = Wc2[n];
#pragma unroll
    for (int ki = 0; ki < 4; ++ki)
      bfrag[ct][ki] = *(const short8*)(WT + n * 128 + ki * 32 + quad * 8);
  }
  const float vbias = bc2[0];
  const int aa = tid & 7;
  const float bmu_a = bmu[aa], blv_a = blv[aa];

  const int t0 = blockIdx.x * ST_TPB;

  float4 rbuf[2];
  {
    const float4* Xv = (const float4*)(state + (size_t)t0 * 32 * D_IN);
    rbuf[0] = Xv[tid]; rbuf[1] = Xv[tid + 512];
  }

  for (int i = 0; i < ST_TPB; ++i) {
    const int r0 = (t0 + i) * 32;

    // ---- stage regs -> LDS bf16 (perm-truncate: 1 op / 2 elems)
#pragma unroll
    for (int j = 0; j < 2; ++j) {
      int e4 = tid + j * 512;
      int row = e4 >> 5, c4 = e4 & 31;
      uint2 u;
      u.x = pack_bf2(rbuf[j].x, rbuf[j].y);
      u.y = pack_bf2(rbuf[j].z, rbuf[j].w);
      *(uint2*)(&sh_x[row * 136 + c4 * 4]) = u;
    }
    __syncthreads();                            // barrier1

    if (i + 1 < ST_TPB) {
      const float4* Xv2 = (const float4*)(state + (size_t)(r0 + 32) * D_IN);
      rbuf[0] = Xv2[tid]; rbuf[1] = Xv2[tid + 512];
    }
    float fa = 0.f, fb = 0.f;
    if (tid < 256) { fa = action[r0 * 8 + tid]; fb = beta_lp[r0 * 8 + tid]; }

    if (role == 0) {
      // ---- critic GEMM + fused head
#pragma unroll
      for (int rt = 0; rt < 2; ++rt) {
        f32x4 acc[4];
#pragma unroll
        for (int ct = 0; ct < 4; ++ct) acc[ct] = (f32x4){0.f, 0.f, 0.f, 0.f};
#pragma unroll
        for (int ki = 0; ki < 4; ++ki) {
          short8 a = *(const short8*)(&sh_x[(rt * 16 + c) * 136 + ki * 32 + quad * 8]);
#pragma unroll
          for (int ct = 0; ct < 4; ++ct)
            acc[ct] = __builtin_amdgcn_mfma_f32_16x16x32_bf16(a, bfrag[ct][ki], acc[ct], 0, 0, 0);
        }
#pragma unroll
        for (int r = 0; r < 4; ++r) {
          float p = 0.f;
#pragma unroll
          for (int ct = 0; ct < 4; ++ct)
            p += tanh_pre(acc[ct][r] + bias_c[ct]) * wc2_c[ct];
          p = row16_sum(p);
          if (c == 15) sh_v[(rt * 16 + quad * 4 + r) * 4 + wl] = p;
        }
      }
    } else {
      // ---- actor GEMM -> sh_h
#pragma unroll
      for (int rt = 0; rt < 2; ++rt) {
        f32x4 acc[4];
#pragma unroll
        for (int ct = 0; ct < 4; ++ct) acc[ct] = (f32x4){0.f, 0.f, 0.f, 0.f};
#pragma unroll
        for (int ki = 0; ki < 4; ++ki) {
          short8 a = *(const short8*)(&sh_x[(rt * 16 + c) * 136 + ki * 32 + quad * 8]);
#pragma unroll
          for (int ct = 0; ct < 4; ++ct)
            acc[ct] = __builtin_amdgcn_mfma_f32_16x16x32_bf16(a, bfrag[ct][ki], acc[ct], 0, 0, 0);
        }
#pragma unroll
        for (int ct = 0; ct < 4; ++ct) {
          int col = wl * 64 + ct * 16 + c;
#pragma unroll
          for (int r = 0; r < 4; ++r) {
            int row = rt * 16 + quad * 4 + r;
            sh_h[row * 264 + col] = bf_trunc(tanh_pre(acc[ct][r] + bias_c[ct]));
          }
        }
      }
    }
    __syncthreads();                            // barrier2

    if (role == 1) {
      // ---- head GEMM: slice wl owns K-cols [wl*64, +64)
#pragma unroll
      for (int st = 0; st < 2; ++st) {
        f32x4 acc2 = (f32x4){0.f, 0.f, 0.f, 0.f};
#pragma unroll
        for (int k2 = 0; k2 < 2; ++k2) {
          int kofs = wl * 64 + k2 * 32 + quad * 8;
          short8 a2 = *(const short8*)(H1 + c * 256 + kofs);
          short8 b2 = *(const short8*)(&sh_h[(st * 16 + c) * 264 + kofs]);
          acc2 = __builtin_amdgcn_mfma_f32_16x16x32_bf16(a2, b2, acc2, 0, 0, 0);
        }
        *((f32x4*)&sh_hb[((wl * 32) + st * 16 + c) * HB_S + quad * 4]) = acc2;
      }
    } else if (tid < 32) {
      v0out[r0 + tid] = sh_v[tid * 4] + sh_v[tid * 4 + 1] + sh_v[tid * 4 + 2] +
                        sh_v[tid * 4 + 3] + vbias;
    }
    __syncthreads();                            // barrier3

    if (tid < 256) {
      int s = tid >> 3;
      float mu = sh_hb[(s)*HB_S + aa]            + sh_hb[(32 + s) * HB_S + aa] +
                 sh_hb[(64 + s) * HB_S + aa]     + sh_hb[(96 + s) * HB_S + aa] + bmu_a;
      float lv = sh_hb[(s)*HB_S + 8 + aa]        + sh_hb[(32 + s) * HB_S + 8 + aa] +
                 sh_hb[(64 + s) * HB_S + 8 + aa] + sh_hb[(96 + s) * HB_S + 8 + aa] + blv_a;
      float d = fa - mu;
      float term = -0.5f * d * d * __expf(-lv) - 0.5f * lv - HALF_LOG_2PI - fb;
      term = xor8_sum(term);
      if (aa == 0) ratio[r0 + s] = __expf(term);
    }
  }
}

// ---------------------------------------------------------------- k_next:
// critic(next_state) -> v1. 2048 persistent blocks x NX_TPB tiles; 256 threads.
__global__ __launch_bounds__(256, 4) void k_next(
    const float* __restrict__ next_state,
    const unsigned short* __restrict__ Wc1Ts,
    const float* __restrict__ bc1, const float* __restrict__ Wc2,
    const float* __restrict__ bc2, float* __restrict__ v1out) {
  const int tid = threadIdx.x;
  const int lane = tid & 63;
  const int wv   = tid >> 6;
  const int c    = lane & 15;
  const int quad = lane >> 4;

  __shared__ unsigned short sh_x[32 * 136];
  __shared__ float sh_v[32 * 4];

  short8 bfrag[4][4];
  float bias_c[4], wc2_c[4];
#pragma unroll
  for (int ct = 0; ct < 4; ++ct) {
    int n = wv * 64 + ct * 16 + c;
    bias_c[ct] = bc1[n] * SCALE2;
    wc2_c[ct]  = Wc2[n];
#pragma unroll
    for (int ki = 0; ki < 4; ++ki)
      bfrag[ct][ki] = *(const short8*)(Wc1Ts + n * 128 + ki * 32 + quad * 8);
  }
  const float vbias = bc2[0];

  const int t0 = blockIdx.x * NX_TPB;
  float4 rbuf[4];
  {
    const float4* Xv = (const float4*)(next_state + (size_t)t0 * 32 * D_IN);
#pragma unroll
    for (int j = 0; j < 4; ++j) rbuf[j] = Xv[tid + j * 256];
  }

  for (int i = 0; i < NX_TPB; ++i) {
    const int r0 = (t0 + i) * 32;
#pragma unroll
    for (int j = 0; j < 4; ++j) {
      int e = tid + j * 256;
      int row = e >> 5, c4 = e & 31;
      uint2 u;
      u.x = pack_bf2(rbuf[j].x, rbuf[j].y);
      u.y = pack_bf2(rbuf[j].z, rbuf[j].w);
      *(uint2*)(&sh_x[row * 136 + c4 * 4]) = u;
    }
    __syncthreads();

    if (i + 1 < NX_TPB) {
      const float4* Xv2 = (const float4*)(next_state + (size_t)(r0 + 32) * D_IN);
#pragma unroll
      for (int j = 0; j < 4; ++j) rbuf[j] = Xv2[tid + j * 256];
    }

#pragma unroll
    for (int rt = 0; rt < 2; ++rt) {
      f32x4 acc[4];
#pragma unroll
      for (int ct = 0; ct < 4; ++ct) acc[ct] = (f32x4){0.f, 0.f, 0.f, 0.f};
#pragma unroll
      for (int ki = 0; ki < 4; ++ki) {
        short8 a = *(const short8*)(&sh_x[(rt * 16 + c) * 136 + ki * 32 + quad * 8]);
#pragma unroll
        for (int ct = 0; ct < 4; ++ct)
          acc[ct] = __builtin_amdgcn_mfma_f32_16x16x32_bf16(a, bfrag[ct][ki], acc[ct], 0, 0, 0);
      }
#pragma unroll
      for (int r = 0; r < 4; ++r) {
        float p = 0.f;
#pragma unroll
        for (int ct = 0; ct < 4; ++ct)
          p += tanh_pre(acc[ct][r] + bias_c[ct]) * wc2_c[ct];
        p = row16_sum(p);
        if (c == 15) sh_v[(rt * 16 + quad * 4 + r) * 4 + wv] = p;
      }
    }
    __syncthreads();
    if (tid < 32) {
      v1out[r0 + tid] = sh_v[tid * 4] + sh_v[tid * 4 + 1] + sh_v[tid * 4 + 2] +
                        sh_v[tid * 4 + 3] + vbias;
    }
  }
}

// ---------------------------------------------------------------- GAE + losses, ONE kernel:
// 256 blocks (== CU count -> guaranteed co-resident; software grid barrier via
// device-scope counters). Each block: 1024 own elems + 1024 lookahead
// (c^1024 ~ 5e-28 -> exact truncation in fp32). adv stays in registers.
__global__ __launch_bounds__(256) void k_gae2(
    const float* __restrict__ reward, const float* __restrict__ v0,
    const float* __restrict__ v1, const float* __restrict__ ratio,
    float* __restrict__ accs, float* __restrict__ out) {
  const int j = blockIdx.x, k = threadIdx.x;
  const int base = j * 1024 + k * 8;
  unsigned int* cnt1 = (unsigned int*)accs + 4;
  unsigned int* cnt2 = (unsigned int*)accs + 5;

  float d[8];
  float s = 0.f, w = 1.f;
#pragma unroll
  for (int i = 0; i < 8; ++i) {
    int idx = base + i;
    float dd = 0.f;
    if (idx < T_N) dd = reward[idx] + GAMMA * v1[idx] - v0[idx];
    d[i] = dd;
    s += w * dd;
    w *= C_GL;
  }
  const float W8 = w;
  __shared__ float Ss[256], Sw[256];
  __shared__ float sh_stats[2];
  Ss[k] = s; Sw[k] = W8;
  __syncthreads();
  for (int st = 1; st < 256; st <<= 1) {
    bool has = (k + st) < 256;
    float ns = 0.f, nw = 0.f;
    if (has) { ns = Ss[k] + Sw[k] * Ss[k + st]; nw = Sw[k] * Sw[k + st]; }
    __syncthreads();
    if (has) { Ss[k] = ns; Sw[k] = nw; }
    __syncthreads();
  }
  float g = (k < 255) ? Ss[k + 1] : 0.f;
  float adv[8];
  float sa = 0.f, sq = 0.f;
  if (k < 128) {
#pragma unroll
    for (int i = 7; i >= 0; --i) {
      g = d[i] + C_GL * g;
      float a = g - v0[base + i];
      adv[i] = a;
      sa += a; sq += a * a;
    }
  }
  __syncthreads();
  Ss[k] = sa; Sw[k] = sq;
  __syncthreads();
  for (int off = 128; off > 0; off >>= 1) {
    if (k < off) { Ss[k] += Ss[k + off]; Sw[k] += Sw[k + off]; }
    __syncthreads();
  }
  if (k == 0) {
    atomicAdd(&accs[0], Ss[0]);                 // Σ adv
    atomicAdd(&accs[1], Sw[0]);                 // Σ adv² (= critic_loss)
    __hip_atomic_fetch_add(cnt1, 1u, __ATOMIC_RELEASE, __HIP_MEMORY_SCOPE_AGENT);
    // ---- software grid barrier (256 blocks co-resident on 256 CUs)
    while (__hip_atomic_load(cnt1, __ATOMIC_ACQUIRE, __HIP_MEMORY_SCOPE_AGENT) < 256u)
      __builtin_amdgcn_s_sleep(4);
    sh_stats[0] = __hip_atomic_load(&accs[0], __ATOMIC_RELAXED, __HIP_MEMORY_SCOPE_AGENT);
    sh_stats[1] = __hip_atomic_load(&accs[1], __ATOMIC_RELAXED, __HIP_MEMORY_SCOPE_AGENT);
  }
  __syncthreads();

  const float sum  = sh_stats[0];
  const float cl   = sh_stats[1];
  const float mean = sum * (1.f / (float)T_N);
  const float var  = (cl - sum * mean) / (float)(T_N - 1);
  const float inv  = 1.f / (sqrtf(var) + 1e-7f);
  float sl = 0.f;
  if (k < 128) {
#pragma unroll
    for (int i = 0; i < 8; ++i) {
      float a = (adv[i] - mean) * inv;
      float r = ratio[base + i];
      float rc = fminf(fmaxf(r, 1.f - EPS_C), 1.f + EPS_C);
      sl += -fminf(r * a, rc * a);
    }
  }
  __syncthreads();
  Ss[k] = sl;
  __syncthreads();
  for (int off = 128; off > 0; off >>= 1) {
    if (k < off) Ss[k] += Ss[k + off];
    __syncthreads();
  }
  if (k == 0) {
    atomicAdd(&accs[2], Ss[0]);                 // actor_loss
    unsigned int old = __hip_atomic_fetch_add(cnt2, 1u, __ATOMIC_ACQ_REL,
                                              __HIP_MEMORY_SCOPE_AGENT);
    if (old == 255u) {
      float al = __hip_atomic_load(&accs[2], __ATOMIC_RELAXED, __HIP_MEMORY_SCOPE_AGENT);
      out[0] = al + cl;                         // actor_loss + critic_loss
    }
  }
}

// ---------------------------------------------------------------- launch
extern "C" void kernel_launch(void* const* d_in, const int* in_sizes, int n_in,
                              void* d_out, int out_size, void* d_ws, size_t ws_size,
                              hipStream_t stream) {
  const float* state      = (const float*)d_in[0];
  const float* next_state = (const float*)d_in[1];
  const float* action     = (const float*)d_in[2];
  const float* beta_lp    = (const float*)d_in[3];
  const float* reward     = (const float*)d_in[4];
  const float* W1   = (const float*)d_in[5];
  const float* b1   = (const float*)d_in[6];
  const float* Wmu  = (const float*)d_in[7];
  const float* bmu  = (const float*)d_in[8];
  const float* Wlv  = (const float*)d_in[9];
  const float* blv  = (const float*)d_in[10];
  const float* Wc1  = (const float*)d_in[11];
  const float* bc1  = (const float*)d_in[12];
  const float* Wc2  = (const float*)d_in[13];
  const float* bc2  = (const float*)d_in[14];

  char* ws = (char*)d_ws;
  size_t o = 0;
  unsigned short* Wc1Ts = (unsigned short*)(ws + o); o += 65536;
  unsigned short* W1Ts  = (unsigned short*)(ws + o); o += 65536;
  unsigned short* H1    = (unsigned short*)(ws + o); o += 8192;
  float* v0    = (float*)(ws + o); o += (size_t)T_N * 4;
  float* v1    = (float*)(ws + o); o += (size_t)T_N * 4;
  float* ratio = (float*)(ws + o); o += (size_t)T_N * 4;
  float* accs  = (float*)(ws + o); o += 256;

  k_prep<<<272, 256, 0, stream>>>(Wc1, W1, Wmu, Wlv, Wc1Ts, W1Ts, H1, accs);

  k_state<<<(T_N / 32) / ST_TPB, 512, 0, stream>>>(
      state, action, beta_lp, Wc1Ts, W1Ts, H1, bc1, b1, Wc2, bc2, bmu, blv,
      v0, ratio);
  k_next<<<(T_N / 32) / NX_TPB, 256, 0, stream>>>(
      next_state, Wc1Ts, bc1, Wc2, bc2, v1);
  k_gae2<<<256, 256, 0, stream>>>(reward, v0, v1, ratio, accs, (float*)d_out);
}